// Round 7
// baseline (5877.983 us; speedup 1.0000x reference)
//
#include <hip/hip_runtime.h>
#include <hip/hip_fp16.h>

typedef unsigned int u32;
typedef unsigned short u16;
typedef unsigned long long u64;

#define BB 64
#define TT 512
#define FF 128
#define HH 512
#define G4 2048  // 4*H

typedef _Float16 f16x8 __attribute__((ext_vector_type(8)));
typedef float f32x4 __attribute__((ext_vector_type(4)));

union UH2 { u32 u; __half2 h; };
__device__ inline __half2 u2h(u32 u) { UH2 t; t.u = u; return t.h; }

__device__ inline float sigm(float x) { return 1.0f / (1.0f + __expf(-x)); }
__device__ inline float tanh_fast(float x) { return 2.0f / (1.0f + __expf(-2.0f * x)) - 1.0f; }

// ---------------------------------------------------------------------------
// Zero BN accumulators (ws poisoned before each call; exchange tags need no
// init: poison hi32 = 0xAAAAAAAA never equals a tag 1..512).
// ---------------------------------------------------------------------------
__global__ __launch_bounds__(256) void zero_init(float* __restrict__ accum)
{
    int tid = threadIdx.x;
    for (int i = tid; i < 2048; i += 256) accum[i] = 0.0f;
}

// ---------------------------------------------------------------------------
// MFMA f16 GEMM: C(f16)[M,2048] = A[M,K] @ B[K,2048] + bias.
// BM=BN=128, BK=32, 256 threads (4 waves in 2x2), 4x4 16x16x32 tiles/wave.
// ---------------------------------------------------------------------------
template <bool A_HALF, bool AFFINE>
__global__ __launch_bounds__(256) void gemm_mfma(
    const void* __restrict__ Av, const float* __restrict__ Bw,
    const float* __restrict__ bias, const float* __restrict__ sc,
    const float* __restrict__ tr, __half* __restrict__ C, int K)
{
    __shared__ _Float16 sA[128 * 40];
    __shared__ _Float16 sB[128 * 40];
    const int tid = threadIdx.x;
    const int bn = blockIdx.x << 7;
    const int bm = blockIdx.y << 7;
    const int w = tid >> 6, l = tid & 63;
    const int mq = w >> 1, nq = w & 1;
    const int am = l & 15, kg = l >> 4;

    const _Float16* apb = sA + (mq * 64 + am) * 40 + kg * 8;
    const _Float16* bpb = sB + (nq * 64 + am) * 40 + kg * 8;

    const int ar = tid >> 1, akc = (tid & 1) * 16;
    const int bnn = tid & 127, bkr = (tid >> 7) * 16;

    f32x4 acc[4][4];
#pragma unroll
    for (int i = 0; i < 4; ++i)
#pragma unroll
        for (int j = 0; j < 4; ++j) acc[i][j] = (f32x4){0.f, 0.f, 0.f, 0.f};

    for (int k0 = 0; k0 < K; k0 += 32) {
        {
            float av[16];
            if constexpr (A_HALF) {
                const __half* Ap = (const __half*)Av + (size_t)(bm + ar) * K + k0 + akc;
                __half tmp[16];
                *(uint4*)&tmp[0] = *(const uint4*)Ap;
                *(uint4*)&tmp[8] = *(const uint4*)(Ap + 8);
#pragma unroll
                for (int i = 0; i < 16; ++i) av[i] = __half2float(tmp[i]);
            } else {
                const float* Ap = (const float*)Av + (size_t)(bm + ar) * K + k0 + akc;
#pragma unroll
                for (int i = 0; i < 16; i += 4) {
                    float4 v = *(const float4*)(Ap + i);
                    av[i] = v.x; av[i + 1] = v.y; av[i + 2] = v.z; av[i + 3] = v.w;
                }
            }
            if constexpr (AFFINE) {
#pragma unroll
                for (int i = 0; i < 16; ++i) av[i] = av[i] * sc[k0 + akc + i] + tr[k0 + akc + i];
            }
            _Float16 st[16];
#pragma unroll
            for (int i = 0; i < 16; ++i) st[i] = (_Float16)av[i];
            *(f16x8*)(sA + ar * 40 + akc) = *(f16x8*)&st[0];
            *(f16x8*)(sA + ar * 40 + akc + 8) = *(f16x8*)&st[8];
        }
        {
            _Float16 st[16];
#pragma unroll
            for (int i = 0; i < 16; ++i)
                st[i] = (_Float16)Bw[(size_t)(k0 + bkr + i) * G4 + bn + bnn];
            *(f16x8*)(sB + bnn * 40 + bkr) = *(f16x8*)&st[0];
            *(f16x8*)(sB + bnn * 40 + bkr + 8) = *(f16x8*)&st[8];
        }
        __syncthreads();
        f16x8 af[4], bf[4];
#pragma unroll
        for (int i = 0; i < 4; ++i) af[i] = *(const f16x8*)(apb + i * 16 * 40);
#pragma unroll
        for (int j = 0; j < 4; ++j) bf[j] = *(const f16x8*)(bpb + j * 16 * 40);
#pragma unroll
        for (int i = 0; i < 4; ++i)
#pragma unroll
            for (int j = 0; j < 4; ++j)
                acc[i][j] = __builtin_amdgcn_mfma_f32_16x16x32_f16(af[i], bf[j], acc[i][j], 0, 0, 0);
        __syncthreads();
    }

#pragma unroll
    for (int i = 0; i < 4; ++i) {
        const int row0 = bm + mq * 64 + i * 16 + kg * 4;
#pragma unroll
        for (int j = 0; j < 4; ++j) {
            const int col = bn + nq * 64 + j * 16 + am;
            const float bv = bias[col];
#pragma unroll
            for (int r = 0; r < 4; ++r) {
                float v = acc[i][j][r] + bv;
                u32 hu = (u32)__half_as_ushort(__float2half(v));
                u32 hn = __shfl_down(hu, 1);
                if ((am & 1) == 0) {
                    u32 pk = hu | (hn << 16);
                    *(u32*)(C + (size_t)(row0 + r) * G4 + col) = pk;
                }
            }
        }
    }
}

// ---------------------------------------------------------------------------
// MFMA LSTM scan v6: fused tag+data u64 protocol, gate-complete waves.
// Grid: 32 blocks = 4 chains (bg) x 8 col-blocks (cb), 512 threads (8 waves).
// Wave w owns 8 hidden cols [cb*64 + w*8, +8). B-frag chain0 cols =
// {gate i, gate f} x 8 hcols; chain1 = {g, o}. After 2x16 MFMA, two
// shfl_xor(8) give each lane all 4 gates for (hcol, 4 batch rows) -> cell
// update entirely in-wave (no zbuf, 1 syncthreads/step, shh double-buffered).
// Exchange word = u64 { tag=t+1 (hi32), 2 f16 h (lo32) }: one atomic store
// publishes data+flag; consumer poll IS the gather (reload only untagged
// words). Double-buffered image on t&1. BN stats fused via shuffles.
// ---------------------------------------------------------------------------
__global__ __launch_bounds__(512, 2) void lstm_scan_mfma(
    const __half* __restrict__ xW,   // [B*T, 2048] f16 (x@Wx + b)
    const float* __restrict__ Wh,    // [512, 2048] f32
    __half* __restrict__ hout,       // [B*T, 512] f16 (plain, for later kernels)
    u64* __restrict__ exch,          // [4 chains][2 parity][4096 words]
    float* __restrict__ accum)       // [sum 512][sumsq 512]
{
    __shared__ _Float16 shh[2][8192];   // frag-major h, chunk ci = kt*64+kq*16+row

    const int tid = threadIdx.x;
    const int cb = blockIdx.x & 7;
    const int bg = blockIdx.x >> 3;
    const int w = tid >> 6, l = tid & 63;
    const int am = l & 15, kq = l >> 4;
    const int amL = am & 7;
    const int hc = cb * 64 + w * 8 + amL;    // global hidden col (per half-wave)

    // ---- one-time: B-frags. chain c2 col n: gate = 2*c2 + (n>>3), hcol amL ----
    f16x8 bfr[2][16];
#pragma unroll
    for (int c2 = 0; c2 < 2; ++c2) {
        const int gatecol = (c2 * 2 + (am >> 3)) * 512 + hc;
#pragma unroll
        for (int kt = 0; kt < 16; ++kt) {
            _Float16 tmp[8];
#pragma unroll
            for (int j = 0; j < 8; ++j)
                tmp[j] = (_Float16)Wh[(size_t)(kt * 32 + kq * 8 + j) * G4 + gatecol];
            bfr[c2][kt] = *(f16x8*)tmp;
        }
    }

    // consumer identity: 2 chunks (row, c0) and (row, c0+32); 4 words each
    const int crow = tid & 15;
    const int c0 = tid >> 4;                  // 0..31
    u64* exb = exch + (size_t)bg * 8192;
    const int off0 = crow * 256 + c0 * 4;
    const int off1 = crow * 256 + (c0 + 32) * 4;

    // producer identity: lanes am<8 own (hcol hc, batches kq*4+r)
    const bool isProd = (am < 8);
    const int wiBase = cb * 32 + w * 4 + (am >> 1);

    float cst[4] = {0.f, 0.f, 0.f, 0.f};
    float ssl = 0.f, sql = 0.f;

    for (int t = 0; t < TT; ++t) {
        // xW loads (prod lanes): 4 gates x 4 batch rows, L2-cached scalars
        float xv[4][4];
        if (isProd) {
#pragma unroll
            for (int r = 0; r < 4; ++r) {
                const __half* xp = xW + ((size_t)(bg * 16 + kq * 4 + r) * TT + t) * G4 + hc;
#pragma unroll
                for (int g = 0; g < 4; ++g) xv[g][r] = __half2float(xp[g * 512]);
            }
        }

        f32x4 a0 = {0.f, 0.f, 0.f, 0.f}, a1 = {0.f, 0.f, 0.f, 0.f};
        if (t > 0) {
            // ---- poll-gather: reload untagged words until tag == t ----
            const u64* ib = exb + ((t - 1) & 1) * 4096;
            const u64* p0 = ib + off0;
            const u64* p1 = ib + off1;
            u64 wv[8];
            u32 need = 0xFFu;
            while (need) {
#pragma unroll
                for (int j = 0; j < 4; ++j) {
                    if (need & (1u << j)) {
                        u64 v = __hip_atomic_load(p0 + j, __ATOMIC_RELAXED, __HIP_MEMORY_SCOPE_AGENT);
                        if ((u32)(v >> 32) == (u32)t) { wv[j] = v; need &= ~(1u << j); }
                    }
                    if (need & (1u << (j + 4))) {
                        u64 v = __hip_atomic_load(p1 + j, __ATOMIC_RELAXED, __HIP_MEMORY_SCOPE_AGENT);
                        if ((u32)(v >> 32) == (u32)t) { wv[j + 4] = v; need &= ~(1u << (j + 4)); }
                    }
                }
            }
            // strip tags -> 16B frag chunks -> LDS (linear, conflict-free)
            uint4 pk0 = {(u32)wv[0], (u32)wv[1], (u32)wv[2], (u32)wv[3]};
            uint4 pk1 = {(u32)wv[4], (u32)wv[5], (u32)wv[6], (u32)wv[7]};
            _Float16* sb = shh[t & 1];
            *(uint4*)(sb + (size_t)tid * 8) = pk0;
            *(uint4*)(sb + (size_t)(tid + 512) * 8) = pk1;
            __syncthreads();

            // ---- MFMA: chain0 = gates {i,f}, chain1 = {g,o} ----
            const _Float16* ap = sb + l * 8;
#pragma unroll
            for (int kt = 0; kt < 16; ++kt) {
                f16x8 av = *(const f16x8*)(ap + kt * 512);
                a0 = __builtin_amdgcn_mfma_f32_16x16x32_f16(av, bfr[0][kt], a0, 0, 0, 0);
                a1 = __builtin_amdgcn_mfma_f32_16x16x32_f16(av, bfr[1][kt], a1, 0, 0, 0);
            }
        }

        // swap gate halves: lane am (<8) gets f from am+8 (chain0), o (chain1)
        f32x4 b0, b1;
#pragma unroll
        for (int r = 0; r < 4; ++r) {
            b0[r] = __shfl_xor(a0[r], 8);
            b1[r] = __shfl_xor(a1[r], 8);
        }

        if (isProd) {
            u16 hq[4];
#pragma unroll
            for (int r = 0; r < 4; ++r) {
                float zi = xv[0][r] + a0[r];
                float zf = xv[1][r] + b0[r];
                float zg = xv[2][r] + a1[r];
                float zo = xv[3][r] + b1[r];
                float ii = sigm(zi), ff = sigm(zf), gg = tanh_fast(zg), oo = sigm(zo);
                cst[r] = ff * cst[r] + ii * gg;
                float hv = oo * tanh_fast(cst[r]);
                ssl += hv; sql += hv * hv;
                hq[r] = __half_as_ushort(__float2half(hv));
            }
            u64* ob = exb + (t & 1) * 4096;
#pragma unroll
            for (int r = 0; r < 4; ++r) {
                u32 hu = hq[r];
                u32 hn = __shfl_xor(hu, 1);
                if ((am & 1) == 0) {
                    u32 pair = hu | (hn << 16);
                    // plain store for GEMM2 / head (read after kernel end)
                    *(u32*)(hout + ((size_t)(bg * 16 + kq * 4 + r) * TT + t) * HH + hc) = pair;
                    // fused tag+data publish: single 8B atomic
                    u64 pk = ((u64)(u32)(t + 1) << 32) | (u64)pair;
                    __hip_atomic_store(ob + (kq * 4 + r) * 256 + wiBase, pk,
                                       __ATOMIC_RELAXED, __HIP_MEMORY_SCOPE_AGENT);
                }
            }
        }
    }

    // ---- fused BN stats: shuffle-reduce over kq (batches), atomicAdd ----
    ssl += __shfl_xor(ssl, 16); ssl += __shfl_xor(ssl, 32);
    sql += __shfl_xor(sql, 16); sql += __shfl_xor(sql, 32);
    if (kq == 0 && am < 8) {
        atomicAdd(&accum[hc], ssl);
        atomicAdd(&accum[HH + hc], sql);
    }
}

__global__ __launch_bounds__(512) void bn_finalize(
    const float* __restrict__ accum, const float* __restrict__ gamma,
    const float* __restrict__ beta, float* __restrict__ s, float* __restrict__ t)
{
    int j = threadIdx.x;
    const float inv = 1.0f / (float)(BB * TT);
    float m = accum[j] * inv;
    float v = accum[HH + j] * inv - m * m;
    float scv = gamma[j] * rsqrtf(v + 1e-5f);
    s[j] = scv;
    t[j] = beta[j] - m * scv;
}

// ---------------------------------------------------------------------------
// Head: out[m] = relu(bn(h2[m,:]) @ Wd1 + bd1) @ Wd2 + bd2
// ---------------------------------------------------------------------------
__global__ __launch_bounds__(256) void head_kernel(
    const __half* __restrict__ h2, const float* __restrict__ s2,
    const float* __restrict__ t2, const float* __restrict__ Wd1,
    const float* __restrict__ bd1, const float* __restrict__ Wd2,
    const float* __restrict__ bd2, float* __restrict__ out)
{
    const int tid = threadIdx.x;
    const int j = tid & 15;
    const int row = blockIdx.x * 16 + (tid >> 4);
    const __half* hr = h2 + (size_t)row * HH;
    float acc = 0.0f;
    for (int k = 0; k < HH; ++k) {
        float a = __half2float(hr[k]) * s2[k] + t2[k];
        acc += a * Wd1[k * 16 + j];
    }
    float r = fmaxf(acc + bd1[j], 0.0f);
    float v = r * Wd2[j];
#pragma unroll
    for (int off = 8; off; off >>= 1) v += __shfl_down(v, off, 16);
    if (j == 0) out[row] = v + bd2[0];
}

// ---------------------------------------------------------------------------
extern "C" void kernel_launch(void* const* d_in, const int* in_sizes, int n_in,
                              void* d_out, int out_size, void* d_ws, size_t ws_size,
                              hipStream_t stream)
{
    const float* x   = (const float*)d_in[0];
    const float* Wx1 = (const float*)d_in[1];
    const float* Wh1 = (const float*)d_in[2];
    const float* b1  = (const float*)d_in[3];
    const float* g1  = (const float*)d_in[4];
    const float* be1 = (const float*)d_in[5];
    const float* Wx2 = (const float*)d_in[6];
    const float* Wh2 = (const float*)d_in[7];
    const float* b2  = (const float*)d_in[8];
    const float* g2  = (const float*)d_in[9];
    const float* be2 = (const float*)d_in[10];
    const float* Wd1 = (const float*)d_in[11];
    const float* bd1 = (const float*)d_in[12];
    const float* Wd2 = (const float*)d_in[13];
    const float* bd2 = (const float*)d_in[14];
    float* out = (float*)d_out;

    char* ws = (char*)d_ws;
    __half* xW    = (__half*)(ws);                   // 128 MiB  [B*T, 2048]
    __half* h1    = (__half*)(ws + 134217728);       // 32 MiB   [B*T, 512]
    __half* h2    = (__half*)(ws + 167772160);       // 32 MiB
    u64*    exch1 = (u64*)   (ws + 201326592);       // 256 KiB exchange (layer 1)
    u64*    exch2 = (u64*)   (ws + 201588736);       // 256 KiB exchange (layer 2)
    float*  accum = (float*) (ws + 201850880);       // 2048 f32
    float*  s1    = (float*) (ws + 201859072);
    float*  t1    = s1 + HH;
    float*  s2    = t1 + HH;
    float*  t2    = s2 + HH;

    const int M = BB * TT;  // 32768

    zero_init<<<1, 256, 0, stream>>>(accum);

    gemm_mfma<false, false><<<dim3(16, M / 128), 256, 0, stream>>>(
        x, Wx1, b1, nullptr, nullptr, xW, FF);

    lstm_scan_mfma<<<32, 512, 0, stream>>>(xW, Wh1, h1, exch1, accum);
    bn_finalize<<<1, 512, 0, stream>>>(accum, g1, be1, s1, t1);

    gemm_mfma<true, true><<<dim3(16, M / 128), 256, 0, stream>>>(
        h1, Wx2, b2, s1, t1, xW, HH);

    lstm_scan_mfma<<<32, 512, 0, stream>>>(xW, Wh2, h2, exch2, accum + 1024);
    bn_finalize<<<1, 512, 0, stream>>>(accum + 1024, g2, be2, s2, t2);

    head_kernel<<<M / 16, 256, 0, stream>>>(h2, s2, t2, Wd1, bd1, Wd2, bd2, out);
}

// Round 8
// 4838.537 us; speedup vs baseline: 1.2148x; 1.2148x over previous
//
#include <hip/hip_runtime.h>
#include <hip/hip_fp16.h>

typedef unsigned int u32;
typedef unsigned short u16;
typedef unsigned long long u64;

#define BB 64
#define TT 512
#define FF 128
#define HH 512
#define G4 2048  // 4*H

typedef _Float16 f16x8 __attribute__((ext_vector_type(8)));
typedef float f32x4 __attribute__((ext_vector_type(4)));

union UH2 { u32 u; __half2 h; };
__device__ inline __half2 u2h(u32 u) { UH2 t; t.u = u; return t.h; }

__device__ inline float sigm(float x) { return 1.0f / (1.0f + __expf(-x)); }
__device__ inline float tanh_fast(float x) { return 2.0f / (1.0f + __expf(-2.0f * x)) - 1.0f; }

// ---------------------------------------------------------------------------
// Zero BN accumulators. Exchange buffers need no init: ws poison hi32
// (0xAAAAAAAA) never equals a tag in 1..512.
// ---------------------------------------------------------------------------
__global__ __launch_bounds__(256) void zero_init(float* __restrict__ accum)
{
    int tid = threadIdx.x;
    for (int i = tid; i < 2048; i += 256) accum[i] = 0.0f;
}

// ---------------------------------------------------------------------------
// MFMA f16 GEMM: C(f16)[M,2048] = A[M,K] @ B[K,2048] + bias.
// BM=BN=128, BK=32, 256 threads (4 waves in 2x2), 4x4 16x16x32 tiles/wave.
// ---------------------------------------------------------------------------
template <bool A_HALF, bool AFFINE>
__global__ __launch_bounds__(256) void gemm_mfma(
    const void* __restrict__ Av, const float* __restrict__ Bw,
    const float* __restrict__ bias, const float* __restrict__ sc,
    const float* __restrict__ tr, __half* __restrict__ C, int K)
{
    __shared__ _Float16 sA[128 * 40];
    __shared__ _Float16 sB[128 * 40];
    const int tid = threadIdx.x;
    const int bn = blockIdx.x << 7;
    const int bm = blockIdx.y << 7;
    const int w = tid >> 6, l = tid & 63;
    const int mq = w >> 1, nq = w & 1;
    const int am = l & 15, kg = l >> 4;

    const _Float16* apb = sA + (mq * 64 + am) * 40 + kg * 8;
    const _Float16* bpb = sB + (nq * 64 + am) * 40 + kg * 8;

    const int ar = tid >> 1, akc = (tid & 1) * 16;
    const int bnn = tid & 127, bkr = (tid >> 7) * 16;

    f32x4 acc[4][4];
#pragma unroll
    for (int i = 0; i < 4; ++i)
#pragma unroll
        for (int j = 0; j < 4; ++j) acc[i][j] = (f32x4){0.f, 0.f, 0.f, 0.f};

    for (int k0 = 0; k0 < K; k0 += 32) {
        {
            float av[16];
            if constexpr (A_HALF) {
                const __half* Ap = (const __half*)Av + (size_t)(bm + ar) * K + k0 + akc;
                __half tmp[16];
                *(uint4*)&tmp[0] = *(const uint4*)Ap;
                *(uint4*)&tmp[8] = *(const uint4*)(Ap + 8);
#pragma unroll
                for (int i = 0; i < 16; ++i) av[i] = __half2float(tmp[i]);
            } else {
                const float* Ap = (const float*)Av + (size_t)(bm + ar) * K + k0 + akc;
#pragma unroll
                for (int i = 0; i < 16; i += 4) {
                    float4 v = *(const float4*)(Ap + i);
                    av[i] = v.x; av[i + 1] = v.y; av[i + 2] = v.z; av[i + 3] = v.w;
                }
            }
            if constexpr (AFFINE) {
#pragma unroll
                for (int i = 0; i < 16; ++i) av[i] = av[i] * sc[k0 + akc + i] + tr[k0 + akc + i];
            }
            _Float16 st[16];
#pragma unroll
            for (int i = 0; i < 16; ++i) st[i] = (_Float16)av[i];
            *(f16x8*)(sA + ar * 40 + akc) = *(f16x8*)&st[0];
            *(f16x8*)(sA + ar * 40 + akc + 8) = *(f16x8*)&st[8];
        }
        {
            _Float16 st[16];
#pragma unroll
            for (int i = 0; i < 16; ++i)
                st[i] = (_Float16)Bw[(size_t)(k0 + bkr + i) * G4 + bn + bnn];
            *(f16x8*)(sB + bnn * 40 + bkr) = *(f16x8*)&st[0];
            *(f16x8*)(sB + bnn * 40 + bkr + 8) = *(f16x8*)&st[8];
        }
        __syncthreads();
        f16x8 af[4], bf[4];
#pragma unroll
        for (int i = 0; i < 4; ++i) af[i] = *(const f16x8*)(apb + i * 16 * 40);
#pragma unroll
        for (int j = 0; j < 4; ++j) bf[j] = *(const f16x8*)(bpb + j * 16 * 40);
#pragma unroll
        for (int i = 0; i < 4; ++i)
#pragma unroll
            for (int j = 0; j < 4; ++j)
                acc[i][j] = __builtin_amdgcn_mfma_f32_16x16x32_f16(af[i], bf[j], acc[i][j], 0, 0, 0);
        __syncthreads();
    }

#pragma unroll
    for (int i = 0; i < 4; ++i) {
        const int row0 = bm + mq * 64 + i * 16 + kg * 4;
#pragma unroll
        for (int j = 0; j < 4; ++j) {
            const int col = bn + nq * 64 + j * 16 + am;
            const float bv = bias[col];
#pragma unroll
            for (int r = 0; r < 4; ++r) {
                float v = acc[i][j][r] + bv;
                u32 hu = (u32)__half_as_ushort(__float2half(v));
                u32 hn = __shfl_down(hu, 1);
                if ((am & 1) == 0) {
                    u32 pk = hu | (hn << 16);
                    *(u32*)(C + (size_t)(row0 + r) * G4 + col) = pk;
                }
            }
        }
    }
}

// ---------------------------------------------------------------------------
// MFMA LSTM scan v7: R6 skeleton + fused tag+data u64 exchange, coalesced.
// Grid: 32 blocks = 4 chains (bg) x 8 col-blocks (cb), 512 threads (8 waves).
// Exchange image per chain per parity: [16 rows][256 colpairs] u64 words
// { tag=t+1 (hi32), 2xf16 h (lo32) }.
// Producer thread (row ub, pair cb*32+uh) -> word ub*256+cb*32+uh:
//   consecutive lanes -> consecutive words (coalesced store). One 8B atomic
//   publishes data+flag -> no drain, no flag store, no end-of-step sync.
// Consumer thread polls words {tid + 512k, k=0..7}: per instruction lane i
//   -> addr i*8 (fully coalesced); reload only untagged words; scatter to
//   frag-major LDS [kt][row][kq] as 8 ds_write_b32 (<=4-way banks).
// Then (unchanged from R6): 2x16 MFMA with reg-resident Wh, zbuf, update
// with coalesced xW u32 loads, BN stats fused.
// ---------------------------------------------------------------------------
__global__ __launch_bounds__(512, 2) void lstm_scan_mfma(
    const __half* __restrict__ xW,   // [B*T, 2048] f16 (x@Wx + b)
    const float* __restrict__ Wh,    // [512, 2048] f32
    __half* __restrict__ hout,       // [B*T, 512] f16 (plain, for GEMM2/head)
    u64* __restrict__ exch,          // [4 chains][2 parity][4096 words]
    float* __restrict__ accum)       // [sum 512][sumsq 512]
{
    __shared__ _Float16 shh[8192];     // 16 KB frag-major: [kt16][row16][kq4] x 8 halves
    __shared__ float zbuf[16 * 260];   // 16.25 KB: z [m16][gc 256 +4]

    const int tid = threadIdx.x;
    const int cb = blockIdx.x & 7;
    const int bg = blockIdx.x >> 3;

    const int w = tid >> 6, l = tid & 63;
    const int am = l & 15, kq = l >> 4;

    // ---- one-time: wave's 32 Wh gate-cols -> 128 VGPRs per lane ----
    f16x8 bfr[2][16];
#pragma unroll
    for (int cg = 0; cg < 2; ++cg) {
        const int gcol = (w >> 1) * 512 + cb * 64 + (w & 1) * 32 + cg * 16 + am;
#pragma unroll
        for (int kt = 0; kt < 16; ++kt) {
            _Float16 tmp[8];
#pragma unroll
            for (int j = 0; j < 8; ++j)
                tmp[j] = (_Float16)Wh[(size_t)(kt * 32 + kq * 8 + j) * G4 + gcol];
            bfr[cg][kt] = *(f16x8*)tmp;
        }
    }

    // update identity: thread owns (row ub, hcols 2uh, 2uh+1)
    const int ub = tid >> 5, uh = tid & 31;
    const size_t growT = (size_t)(bg * 16 + ub) * TT;

    // exchange bases
    u64* exb = exch + (size_t)bg * 8192;
    const int myword = ub * 256 + cb * 32 + uh;

    // consumer scatter identity: colpair cp fixed, 8 rows of parity row0
    const int cp = tid & 255, row0 = tid >> 8;
    const int skt = cp >> 4, skq = (cp >> 2) & 3, sj = (cp & 3) * 2;
    const int sbase = skt * 512 + skq * 8 + sj;   // + row*32

    float cst0 = 0.f, cst1 = 0.f;
    float ss0 = 0.f, ss1 = 0.f, sq0 = 0.f, sq1 = 0.f;

    for (int t = 0; t < TT; ++t) {
        // xW prefetch: 4 gates x packed pair (L2-cached, coalesced)
        const u32* xp = (const u32*)(xW + (growT + t) * G4) + cb * 32 + uh;
        u32 xi = xp[0], xf = xp[256], xg = xp[512], xo = xp[768];

        if (t > 0) {
            // ---- fused poll-gather: 8 coalesced words, reload untagged ----
            const u64* ib = exb + ((t - 1) & 1) * 4096 + tid;
            u64 wv[8];
            u32 need = 0xFFu;
            while (need) {
#pragma unroll
                for (int k = 0; k < 8; ++k) {
                    if (need & (1u << k)) {
                        u64 v = __hip_atomic_load(ib + k * 512, __ATOMIC_RELAXED,
                                                  __HIP_MEMORY_SCOPE_AGENT);
                        if ((u32)(v >> 32) == (u32)t) { wv[k] = v; need &= ~(1u << k); }
                    }
                }
            }
            // scatter to frag-major LDS: 8 x b32 (cols 2cp,2cp+1; rows row0+2k)
#pragma unroll
            for (int k = 0; k < 8; ++k) {
                int row = row0 + 2 * k;
                *(u32*)(shh + sbase + row * 32) = (u32)wv[k];
            }
            __syncthreads();

            // ---- MFMA: 2 col-group chains, bank-uniform A-frag reads ----
            f32x4 a0 = {0.f, 0.f, 0.f, 0.f}, a1 = {0.f, 0.f, 0.f, 0.f};
            const _Float16* ap = shh + am * 32 + kq * 8;
#pragma unroll
            for (int kt = 0; kt < 16; ++kt) {
                f16x8 av = *(const f16x8*)(ap + kt * 512);
                a0 = __builtin_amdgcn_mfma_f32_16x16x32_f16(av, bfr[0][kt], a0, 0, 0, 0);
                a1 = __builtin_amdgcn_mfma_f32_16x16x32_f16(av, bfr[1][kt], a1, 0, 0, 0);
            }
            const int zc = (w >> 1) * 64 + (w & 1) * 32 + am;
#pragma unroll
            for (int r = 0; r < 4; ++r) {
                zbuf[(kq * 4 + r) * 260 + zc] = a0[r];
                zbuf[(kq * 4 + r) * 260 + zc + 16] = a1[r];
            }
            __syncthreads();
        }

        // ---- gate update: 2 cells per thread ----
        __half2 hxi = u2h(xi), hxf = u2h(xf), hxg = u2h(xg), hxo = u2h(xo);
        float zi0 = __low2float(hxi), zi1 = __high2float(hxi);
        float zf0 = __low2float(hxf), zf1 = __high2float(hxf);
        float zg0 = __low2float(hxg), zg1 = __high2float(hxg);
        float zo0 = __low2float(hxo), zo1 = __high2float(hxo);
        if (t > 0) {
            const float* zr = zbuf + ub * 260 + 2 * uh;
            zi0 += zr[0];   zi1 += zr[1];
            zf0 += zr[64];  zf1 += zr[65];
            zg0 += zr[128]; zg1 += zr[129];
            zo0 += zr[192]; zo1 += zr[193];
        }
        float i0 = sigm(zi0), f0 = sigm(zf0), g0 = tanh_fast(zg0), o0 = sigm(zo0);
        float i1 = sigm(zi1), f1 = sigm(zf1), g1 = tanh_fast(zg1), o1 = sigm(zo1);
        cst0 = f0 * cst0 + i0 * g0;
        cst1 = f1 * cst1 + i1 * g1;
        float h0 = o0 * tanh_fast(cst0);
        float h1 = o1 * tanh_fast(cst1);
        ss0 += h0; sq0 += h0 * h0; ss1 += h1; sq1 += h1 * h1;

        u32 pair = (u32)__half_as_ushort(__float2half(h0)) |
                   ((u32)__half_as_ushort(__float2half(h1)) << 16);

        // fused tag+data publish: single 8B atomic, fire-and-forget
        u64 pk = ((u64)(u32)(t + 1) << 32) | (u64)pair;
        __hip_atomic_store(exb + (t & 1) * 4096 + myword, pk,
                           __ATOMIC_RELAXED, __HIP_MEMORY_SCOPE_AGENT);
        // plain store for GEMM2 / head (read after kernel end, off-path)
        *(u32*)(hout + (growT + t) * HH + cb * 64) + 0;  // no-op guard
        *((u32*)(hout + (growT + t) * HH + cb * 64) + uh) = pair;
    }

    // ---- fused BN stats ----
    __syncthreads();
    float* red = zbuf;
    red[ub * 64 + 2 * uh] = ss0;
    red[ub * 64 + 2 * uh + 1] = ss1;
    __syncthreads();
    if (tid < 64) {
        float s = 0.f;
#pragma unroll
        for (int b = 0; b < 16; ++b) s += red[b * 64 + tid];
        atomicAdd(&accum[cb * 64 + tid], s);
    }
    __syncthreads();
    red[ub * 64 + 2 * uh] = sq0;
    red[ub * 64 + 2 * uh + 1] = sq1;
    __syncthreads();
    if (tid < 64) {
        float s = 0.f;
#pragma unroll
        for (int b = 0; b < 16; ++b) s += red[b * 64 + tid];
        atomicAdd(&accum[HH + cb * 64 + tid], s);
    }
}

__global__ __launch_bounds__(512) void bn_finalize(
    const float* __restrict__ accum, const float* __restrict__ gamma,
    const float* __restrict__ beta, float* __restrict__ s, float* __restrict__ t)
{
    int j = threadIdx.x;
    const float inv = 1.0f / (float)(BB * TT);
    float m = accum[j] * inv;
    float v = accum[HH + j] * inv - m * m;
    float scv = gamma[j] * rsqrtf(v + 1e-5f);
    s[j] = scv;
    t[j] = beta[j] - m * scv;
}

// ---------------------------------------------------------------------------
// Head: out[m] = relu(bn(h2[m,:]) @ Wd1 + bd1) @ Wd2 + bd2
// ---------------------------------------------------------------------------
__global__ __launch_bounds__(256) void head_kernel(
    const __half* __restrict__ h2, const float* __restrict__ s2,
    const float* __restrict__ t2, const float* __restrict__ Wd1,
    const float* __restrict__ bd1, const float* __restrict__ Wd2,
    const float* __restrict__ bd2, float* __restrict__ out)
{
    const int tid = threadIdx.x;
    const int j = tid & 15;
    const int row = blockIdx.x * 16 + (tid >> 4);
    const __half* hr = h2 + (size_t)row * HH;
    float acc = 0.0f;
    for (int k = 0; k < HH; ++k) {
        float a = __half2float(hr[k]) * s2[k] + t2[k];
        acc += a * Wd1[k * 16 + j];
    }
    float r = fmaxf(acc + bd1[j], 0.0f);
    float v = r * Wd2[j];
#pragma unroll
    for (int off = 8; off; off >>= 1) v += __shfl_down(v, off, 16);
    if (j == 0) out[row] = v + bd2[0];
}

// ---------------------------------------------------------------------------
extern "C" void kernel_launch(void* const* d_in, const int* in_sizes, int n_in,
                              void* d_out, int out_size, void* d_ws, size_t ws_size,
                              hipStream_t stream)
{
    const float* x   = (const float*)d_in[0];
    const float* Wx1 = (const float*)d_in[1];
    const float* Wh1 = (const float*)d_in[2];
    const float* b1  = (const float*)d_in[3];
    const float* g1  = (const float*)d_in[4];
    const float* be1 = (const float*)d_in[5];
    const float* Wx2 = (const float*)d_in[6];
    const float* Wh2 = (const float*)d_in[7];
    const float* b2  = (const float*)d_in[8];
    const float* g2  = (const float*)d_in[9];
    const float* be2 = (const float*)d_in[10];
    const float* Wd1 = (const float*)d_in[11];
    const float* bd1 = (const float*)d_in[12];
    const float* Wd2 = (const float*)d_in[13];
    const float* bd2 = (const float*)d_in[14];
    float* out = (float*)d_out;

    char* ws = (char*)d_ws;
    __half* xW    = (__half*)(ws);                   // 128 MiB  [B*T, 2048]
    __half* h1    = (__half*)(ws + 134217728);       // 32 MiB   [B*T, 512]
    __half* h2    = (__half*)(ws + 167772160);       // 32 MiB
    u64*    exch1 = (u64*)   (ws + 201326592);       // 256 KiB exchange (layer 1)
    u64*    exch2 = (u64*)   (ws + 201588736);       // 256 KiB exchange (layer 2)
    float*  accum = (float*) (ws + 201850880);       // 2048 f32
    float*  s1    = (float*) (ws + 201859072);
    float*  t1    = s1 + HH;
    float*  s2    = t1 + HH;
    float*  t2    = s2 + HH;

    const int M = BB * TT;  // 32768

    zero_init<<<1, 256, 0, stream>>>(accum);

    gemm_mfma<false, false><<<dim3(16, M / 128), 256, 0, stream>>>(
        x, Wx1, b1, nullptr, nullptr, xW, FF);

    lstm_scan_mfma<<<32, 512, 0, stream>>>(xW, Wh1, h1, exch1, accum);
    bn_finalize<<<1, 512, 0, stream>>>(accum, g1, be1, s1, t1);

    gemm_mfma<true, true><<<dim3(16, M / 128), 256, 0, stream>>>(
        h1, Wx2, b2, s1, t1, xW, HH);

    lstm_scan_mfma<<<32, 512, 0, stream>>>(xW, Wh2, h2, exch2, accum + 1024);
    bn_finalize<<<1, 512, 0, stream>>>(accum + 1024, g2, be2, s2, t2);

    head_kernel<<<M / 16, 256, 0, stream>>>(h2, s2, t2, Wd1, bd1, Wd2, bd2, out);
}